// Round 10
// baseline (1319.279 us; speedup 1.0000x reference)
//
#include <hip/hip_runtime.h>
#include <hip/hip_bf16.h>
#include <cstdint>

// ---------------------------------------------------------------------------
// Types / helpers
// ---------------------------------------------------------------------------
typedef float  f32x4 __attribute__((ext_vector_type(4)));
typedef short  s16x8 __attribute__((ext_vector_type(8)));
typedef unsigned short u16;
typedef u16    u16x4 __attribute__((ext_vector_type(4)));

__device__ __forceinline__ u16 f2bf(float f) {
    union { float f; uint32_t u; } v; v.f = f;
    uint32_t r = (v.u + 0x7FFFu + ((v.u >> 16) & 1u)) >> 16;   // RNE
    return (u16)r;
}
__device__ __forceinline__ float bf2f(u16 h) {
    union { uint32_t u; float f; } v; v.u = ((uint32_t)h) << 16;
    return v.f;
}

// async global->LDS, 16B per lane. LDS dest must be wave-uniform base;
// HW adds lane*16 (guide §5 / m97, m104).
__device__ __forceinline__ void gl_lds16(const void* g, void* l) {
    __builtin_amdgcn_global_load_lds(
        (const __attribute__((address_space(1))) void*)g,
        (__attribute__((address_space(3))) void*)l, 16, 0, 0);
}

// inline-asm MFMA (avoids builtin operand-type differences across ROCm)
__device__ __forceinline__ void mfma_bf16(f32x4& d, s16x8 a, s16x8 b) {
    asm("v_mfma_f32_16x16x32_bf16 %0, %1, %2, %0" : "+v"(d) : "v"(a), "v"(b));
}

// ---------------------------------------------------------------------------
// Problem constants
// ---------------------------------------------------------------------------
constexpr int S_  = 2048;
constexpr int D_  = 2048;
constexpr int H_  = 16;
constexpr int HD_ = 128;
constexpr int NQKV_ = (16 + 2 * 16) * 128;   // 6144
constexpr int FF_ = 8192;
constexpr int WINDOW_ = 256;
constexpr float EPS_ = 1e-5f;
constexpr float SCALE_ = 0.08838834764831845f; // 1/sqrt(128)

// ---------------------------------------------------------------------------
// Fused fp32 -> bf16 convert of ALL 5 weight matrices, 4 elts/thread.
// ---------------------------------------------------------------------------
constexpr size_t CVT_B0 = 12582912;              // wqkv  (6144*2048)
constexpr size_t CVT_B1 = CVT_B0 + 4194304;      // + wo  (2048*2048)
constexpr size_t CVT_B2 = CVT_B1 + 16777216;     // + w1  (8192*2048)
constexpr size_t CVT_B3 = CVT_B2 + 16777216;     // + w3
constexpr size_t CVT_B4 = CVT_B3 + 16777216;     // + w2  = 67108864
__global__ void k_cvt_all(const float* __restrict__ s0, const float* __restrict__ s1,
                          const float* __restrict__ s2, const float* __restrict__ s3,
                          const float* __restrict__ s4,
                          u16* __restrict__ d0, u16* __restrict__ d1,
                          u16* __restrict__ d2, u16* __restrict__ d3,
                          u16* __restrict__ d4) {
    size_t i = ((size_t)blockIdx.x * blockDim.x + threadIdx.x) * 4;
    const float* s; u16* d; size_t off;
    if      (i < CVT_B0) { s = s0; d = d0; off = i; }
    else if (i < CVT_B1) { s = s1; d = d1; off = i - CVT_B0; }
    else if (i < CVT_B2) { s = s2; d = d2; off = i - CVT_B1; }
    else if (i < CVT_B3) { s = s3; d = d3; off = i - CVT_B2; }
    else                 { s = s4; d = d4; off = i - CVT_B3; }
    float4 v = *(const float4*)(s + off);
    u16x4 o;
    o[0] = f2bf(v.x); o[1] = f2bf(v.y); o[2] = f2bf(v.z); o[3] = f2bf(v.w);
    *(u16x4*)(d + off) = o;
}

// ---------------------------------------------------------------------------
// Row RMSNorm (D=2048): one block / row, 256 threads, 8 elts/thread, bf16 out
// ---------------------------------------------------------------------------
__global__ void k_rmsnorm(const float* __restrict__ x, const float* __restrict__ w,
                          u16* __restrict__ out) {
    int row = blockIdx.x, t = threadIdx.x;
    const float* xr = x + (size_t)row * D_;
    float4 v0 = *(const float4*)(xr + t * 8);
    float4 v1 = *(const float4*)(xr + t * 8 + 4);
    float ss = v0.x*v0.x + v0.y*v0.y + v0.z*v0.z + v0.w*v0.w
             + v1.x*v1.x + v1.y*v1.y + v1.z*v1.z + v1.w*v1.w;
    #pragma unroll
    for (int m = 32; m; m >>= 1) ss += __shfl_xor(ss, m);
    __shared__ float red[4];
    if ((t & 63) == 0) red[t >> 6] = ss;
    __syncthreads();
    float tot = red[0] + red[1] + red[2] + red[3];
    float sc = rsqrtf(tot * (1.0f / D_) + EPS_);
    float4 w0 = *(const float4*)(w + t * 8);
    float4 w1 = *(const float4*)(w + t * 8 + 4);
    s16x8 o;
    o[0] = (short)f2bf(v0.x * sc * w0.x); o[1] = (short)f2bf(v0.y * sc * w0.y);
    o[2] = (short)f2bf(v0.z * sc * w0.z); o[3] = (short)f2bf(v0.w * sc * w0.w);
    o[4] = (short)f2bf(v1.x * sc * w1.x); o[5] = (short)f2bf(v1.y * sc * w1.y);
    o[6] = (short)f2bf(v1.z * sc * w1.z); o[7] = (short)f2bf(v1.w * sc * w1.w);
    *(s16x8*)(out + (size_t)row * D_ + t * 8) = o;
}

// ---------------------------------------------------------------------------
// NT GEMM: C[M][N] = A[M][K] * B[N][K]^T  (A,B bf16, acc fp32)
// m97 structure: 128xBN tile, BK=64, 4 waves, global_load_lds(16B) staging.
// EPI: add fp32 residual. OBF: write bf16. GLU: out = silu(acc)*g3 (bf16).
// ---------------------------------------------------------------------------
template <int BN, int EPI, int OBF, int GLU>
__global__ __launch_bounds__(256) void k_gemm(
        const u16* __restrict__ A, const u16* __restrict__ B,
        float* __restrict__ Cf, u16* __restrict__ Cb,
        const float* __restrict__ res, const u16* __restrict__ g3,
        int M, int N, int K) {
    constexpr int NN = BN / 32;            // B sub-tiles per wave (4 or 2)
    __shared__ u16 sA[128 * 64];
    __shared__ u16 sB[BN * 64];
    int bn = blockIdx.x, bm = blockIdx.y;
    int t = threadIdx.x, l = t & 63, w = t >> 6;
    int wr = w >> 1, wc = w & 1;           // wave tile: 64 x (16*NN)
    f32x4 acc[4][NN] = {};
    const int lrow = l >> 3;               // 0..7 (row within 8-row segment)
    const int lcol = (l & 7) * 8;          // 0..56 (k offset, 8 bf16 = 16B)
    const size_t abase = (size_t)(bm * 128) * K;
    const size_t bbase = (size_t)(bn * BN) * K;

    for (int kt = 0; kt < K; kt += 64) {
        #pragma unroll
        for (int i = 0; i < 4; ++i) {                 // A: 16 segs of 8 rows
            int seg = w * 4 + i;
            gl_lds16(A + abase + (size_t)(seg * 8 + lrow) * K + kt + lcol, &sA[seg * 512]);
        }
        #pragma unroll
        for (int i = 0; i < BN / 32; ++i) {           // B: BN/8 segs
            int seg = w * (BN / 32) + i;
            gl_lds16(B + bbase + (size_t)(seg * 8 + lrow) * K + kt + lcol, &sB[seg * 512]);
        }
        asm volatile("s_waitcnt vmcnt(0)" ::: "memory");
        __syncthreads();
        #pragma unroll
        for (int kk = 0; kk < 2; ++kk) {
            s16x8 af[4], bfr[NN];
            #pragma unroll
            for (int m = 0; m < 4; ++m)
                af[m] = *(const s16x8*)&sA[(wr*64 + m*16 + (l & 15)) * 64 + kk*32 + (l >> 4)*8];
            #pragma unroll
            for (int n = 0; n < NN; ++n)
                bfr[n] = *(const s16x8*)&sB[(wc*16*NN + n*16 + (l & 15)) * 64 + kk*32 + (l >> 4)*8];
            #pragma unroll
            for (int m = 0; m < 4; ++m)
                #pragma unroll
                for (int n = 0; n < NN; ++n)
                    mfma_bf16(acc[m][n], af[m], bfr[n]);
        }
        __syncthreads();
    }
    // epilogue: C row=(l>>4)*4+reg, col=l&15 (verified m89/m91)
    int r0 = bm * 128 + wr * 64, c0 = bn * BN + wc * 16 * NN;
    #pragma unroll
    for (int m = 0; m < 4; ++m)
        #pragma unroll
        for (int n = 0; n < NN; ++n)
            #pragma unroll
            for (int r = 0; r < 4; ++r) {
                int row = r0 + m * 16 + (l >> 4) * 4 + r;
                int col = c0 + n * 16 + (l & 15);
                float v = acc[m][n][r];
                if (EPI) v += res[(size_t)row * N + col];
                if (GLU) {
                    float x3 = bf2f(g3[(size_t)row * N + col]);
                    v = (v / (1.f + __expf(-v))) * x3;     // silu(ff1)*ff3
                    Cb[(size_t)row * N + col] = f2bf(v);
                } else if (OBF) {
                    Cb[(size_t)row * N + col] = f2bf(v);
                } else {
                    Cf[(size_t)row * N + col] = v;
                }
            }
}

// ---------------------------------------------------------------------------
// QKV postprocess (fp32 input): per-head RMSNorm(q,k) + RoPE + relayout to
// [h][s][hd] bf16. One block per sequence position.
// ---------------------------------------------------------------------------
__global__ void k_qkv_post(const float* __restrict__ qkv, const float* __restrict__ fc,
                           const float* __restrict__ qw, const float* __restrict__ kw,
                           u16* __restrict__ qh, u16* __restrict__ kh, u16* __restrict__ vh) {
    int s = blockIdx.x, t = threadIdx.x, w = t >> 6, l = t & 63;
    const float* rowp = qkv + (size_t)s * NQKV_;
    for (int u = w; u < 48; u += 4) {
        int type = u >> 4, h = u & 15;
        const float* p = rowp + type * 2048 + h * HD_;
        if (type < 2) {
            float x0 = p[l], x1 = p[l + 64];               // RoPE halves (d, d+64)
            float ss = x0 * x0 + x1 * x1;
            #pragma unroll
            for (int m = 32; m; m >>= 1) ss += __shfl_xor(ss, m);
            float sc = rsqrtf(ss * (1.0f / HD_) + EPS_);
            const float* nw = (type == 0) ? qw : kw;
            float nr = x0 * sc * nw[l], ni = x1 * sc * nw[l + 64];
            float2 cs = *(const float2*)(fc + ((size_t)s * 64 + l) * 2);
            float o_r = nr * cs.x - ni * cs.y;     // out[2l]
            float o_i = ni * cs.x + nr * cs.y;     // out[2l+1]
            u16* dst = ((type == 0) ? qh : kh) + ((size_t)h * S_ + s) * HD_ + 2 * l;
            *(uint32_t*)dst = (uint32_t)f2bf(o_r) | ((uint32_t)f2bf(o_i) << 16);
        } else {
            float2 vv = *(const float2*)(p + 2 * l);
            u16* dst = vh + ((size_t)h * S_ + s) * HD_ + 2 * l;
            *(uint32_t*)dst = (uint32_t)f2bf(vv.x) | ((uint32_t)f2bf(vv.y) << 16);
        }
    }
}

// ---------------------------------------------------------------------------
// NAIVE sliding-window attention (bisection probe): one wave per (q, head).
// Independently-derived decomposition: lane=dim (l, l+64), scalar fp32
// online softmax, full-wave shuffle dot products. No MFMA, no LDS.
// ---------------------------------------------------------------------------
__global__ __launch_bounds__(256) void k_attn_naive(
        const u16* __restrict__ qh, const u16* __restrict__ kh,
        const u16* __restrict__ vh, u16* __restrict__ y) {
    int h = blockIdx.y;
    int q = blockIdx.x * 4 + (threadIdx.x >> 6);
    int l = threadIdx.x & 63;
    const u16* qp = qh + ((size_t)h * S_ + q) * HD_;
    const u16* kp = kh + (size_t)h * S_ * HD_;
    const u16* vp = vh + (size_t)h * S_ * HD_;
    float q0 = bf2f(qp[l]), q1 = bf2f(qp[l + 64]);
    float o0 = 0.f, o1 = 0.f, m = -1e30f, sum = 0.f;
    int j0 = (q >= WINDOW_ - 1) ? q - (WINDOW_ - 1) : 0;   // j in [q-255, q]
    for (int j = j0; j <= q; ++j) {
        const u16* kr = kp + (size_t)j * HD_;
        float part = q0 * bf2f(kr[l]) + q1 * bf2f(kr[l + 64]);
        #pragma unroll
        for (int s = 32; s; s >>= 1) part += __shfl_xor(part, s);
        float sv = part * SCALE_;
        float mn = fmaxf(m, sv);
        float rescale = __expf(m - mn);    // first iter: exp(-huge) = 0
        float p = __expf(sv - mn);
        o0 *= rescale; o1 *= rescale;
        sum = sum * rescale + p;
        m = mn;
        const u16* vr = vp + (size_t)j * HD_;
        o0 += p * bf2f(vr[l]);
        o1 += p * bf2f(vr[l + 64]);
    }
    float inv = 1.f / sum;
    u16* dst = y + (size_t)q * D_ + h * HD_;
    dst[l]      = f2bf(o0 * inv);
    dst[l + 64] = f2bf(o1 * inv);
}

// ---------------------------------------------------------------------------
// Orchestration
// ---------------------------------------------------------------------------
extern "C" void kernel_launch(void* const* d_in, const int* in_sizes, int n_in,
                              void* d_out, int out_size, void* d_ws, size_t ws_size,
                              hipStream_t stream) {
    (void)in_sizes; (void)n_in; (void)out_size; (void)ws_size;
    const float* x    = (const float*)d_in[0];
    // d_in[1] = input_pos (arange, unused), d_in[3] = mask (computed analytically)
    const float* fc   = (const float*)d_in[2];
    const float* wqkv = (const float*)d_in[4];
    const float* wo   = (const float*)d_in[5];
    const float* qw   = (const float*)d_in[6];
    const float* kw   = (const float*)d_in[7];
    const float* anw  = (const float*)d_in[8];
    const float* fnw  = (const float*)d_in[9];
    const float* w1   = (const float*)d_in[10];
    const float* w3   = (const float*)d_in[11];
    const float* w2   = (const float*)d_in[12];
    float* out = (float*)d_out;
    char* ws = (char*)d_ws;

    // ---- workspace layout (aliased; ~260 MiB total) ----
    size_t o = 0;
    auto take = [&](size_t bytes) { size_t r = o; o += (bytes + 255) & ~(size_t)255; return r; };
    u16*   wqkv_b = (u16*)(ws + take((size_t)NQKV_ * D_ * 2));
    u16*   wo_b   = (u16*)(ws + take((size_t)D_ * D_ * 2));
    u16*   w1_b   = (u16*)(ws + take((size_t)FF_ * D_ * 2));
    u16*   w3_b   = (u16*)(ws + take((size_t)FF_ * D_ * 2));
    u16*   w2_b   = (u16*)(ws + take((size_t)D_ * FF_ * 2));
    float* h_f    = (float*)(ws + take((size_t)S_ * D_ * 4));
    char*  r2     = ws + take((size_t)S_ * D_ * 2);            // nx, then y
    char*  r1     = ws + take(2 * (size_t)S_ * FF_ * 2);       // qkv_f, then g/ff3
    char*  r3     = ws + take(4 * (size_t)S_ * D_ * 2);        // q/k/v/nh
    u16*   nx_b  = (u16*)r2;
    u16*   y_b   = (u16*)r2;                                   // alias (nx dead)
    float* qkv_f = (float*)r1;                                 // 50.3 MB, dead after step 4
    u16*   g_b   = (u16*)r1;                                   // alias (qkv dead)
    u16*   ff3_b = (u16*)(r1 + (size_t)S_ * FF_ * 2);
    // per-head bufs: H*S*HD == S*D here (H*HD == D)
    u16*   qh_b  = (u16*)r3;
    u16*   kh_b  = (u16*)(r3 + 1 * (size_t)S_ * D_ * 2);
    u16*   vh_b  = (u16*)(r3 + 2 * (size_t)S_ * D_ * 2);
    u16*   nh_b  = (u16*)(r3 + 3 * (size_t)S_ * D_ * 2);

    dim3 b256(256);

    // 1) all weight conversions fp32->bf16 in one dispatch (64Mi elts / 4)
    k_cvt_all<<<dim3(65536), b256, 0, stream>>>(
        wqkv, wo, w1, w3, w2, wqkv_b, wo_b, w1_b, w3_b, w2_b);

    // 2) attn rmsnorm -> nx (bf16)
    k_rmsnorm<<<dim3(S_), b256, 0, stream>>>(x, anw, nx_b);

    // 3) qkv = nx @ wqkv^T  (fp32 out)  [768 blocks]
    k_gemm<128, 0, 0, 0><<<dim3(NQKV_ / 128, S_ / 128), b256, 0, stream>>>(
        nx_b, wqkv_b, qkv_f, nullptr, nullptr, nullptr, S_, NQKV_, D_);

    // 4) qk-norm + rope + relayout
    k_qkv_post<<<dim3(S_), b256, 0, stream>>>(qkv_f, fc, qw, kw, qh_b, kh_b, vh_b);

    // 5) sliding-window attention (naive bisection probe) -> y (bf16)
    k_attn_naive<<<dim3(S_ / 4, H_), b256, 0, stream>>>(qh_b, kh_b, vh_b, y_b);

    // 6) h = x + y @ wo^T  (fp32)  [BN=64: 512 blocks]
    k_gemm<64, 1, 0, 0><<<dim3(D_ / 64, S_ / 128), b256, 0, stream>>>(
        y_b, wo_b, h_f, nullptr, x, nullptr, S_, D_, D_);

    // 7) ffn rmsnorm -> nh (bf16)
    k_rmsnorm<<<dim3(S_), b256, 0, stream>>>(h_f, fnw, nh_b);

    // 8a) ff3 = nh @ w3^T (bf16)  [1024 blocks]
    k_gemm<128, 0, 1, 0><<<dim3(FF_ / 128, S_ / 128), b256, 0, stream>>>(
        nh_b, w3_b, nullptr, ff3_b, nullptr, nullptr, S_, FF_, D_);

    // 8b) g = silu(nh @ w1^T) * ff3  (fused GLU epilogue)  [1024 blocks]
    k_gemm<128, 0, 1, 1><<<dim3(FF_ / 128, S_ / 128), b256, 0, stream>>>(
        nh_b, w1_b, nullptr, g_b, nullptr, ff3_b, S_, FF_, D_);

    // 9) out = h + g @ w2^T  (fp32)  [BN=64: 512 blocks, K=8192]
    k_gemm<64, 1, 0, 0><<<dim3(D_ / 64, S_ / 128), b256, 0, stream>>>(
        g_b, w2_b, out, nullptr, h_f, nullptr, S_, D_, FF_);
}